// Round 7
// baseline (731.614 us; speedup 1.0000x reference)
//
#include <hip/hip_runtime.h>

#define BB 4
#define SS 2048
#define DD 2048
#define HH 16
#define DHD 128
#define MAXL 1024

typedef __bf16 bf16x8 __attribute__((ext_vector_type(8)));
typedef float f32x4 __attribute__((ext_vector_type(4)));
typedef unsigned int u32_as1 __attribute__((address_space(1)));
typedef unsigned int u32_as3 __attribute__((address_space(3)));

__device__ __forceinline__ unsigned short f2bf(float f) {
  unsigned int u = __builtin_bit_cast(unsigned int, f);
  u += 0x7fffu + ((u >> 16) & 1u);   // RNE
  return (unsigned short)(u >> 16);
}
__device__ __forceinline__ float bf2f(unsigned short h) {
  unsigned int u = ((unsigned int)h) << 16;
  return __builtin_bit_cast(float, u);
}
union U4 { uint4 u; bf16x8 b; };
__device__ __forceinline__ bf16x8 ldfrag(const unsigned short* p) {
  U4 x; x.u = *(const uint4*)p; return x.b;
}
__device__ __forceinline__ void gl_lds16(const void* g, void* l) {
  __builtin_amdgcn_global_load_lds((const u32_as1*)g, (u32_as3*)l, 16, 0, 0);
}

// DPP 16-lane butterfly reduction (VALU pipe).
template <int C>
__device__ __forceinline__ float dppf(float x) {
  return __builtin_bit_cast(float,
      __builtin_amdgcn_mov_dpp(__builtin_bit_cast(int, x), C, 0xF, 0xF, true));
}
__device__ __forceinline__ float rmax16(float x) {
  x = fmaxf(x, dppf<0xB1>(x));
  x = fmaxf(x, dppf<0x4E>(x));
  x = fmaxf(x, dppf<0x141>(x));
  x = fmaxf(x, dppf<0x140>(x));
  return x;
}
__device__ __forceinline__ float radd16(float x) {
  x += dppf<0xB1>(x);
  x += dppf<0x4E>(x);
  x += dppf<0x141>(x);
  x += dppf<0x140>(x);
  return x;
}

// ---------------------------------------------------------------------------
// Fused preprocessing: blocks [0, NCVT) fp32->bf16 convert of q/k/v sources;
// [NCVT, NCVT+NTW) weight transpose (4 matrices); [NCVT+NTW, +4) build_pos.
#define NCVT 40960   // (BB*MAXL*DD + 2*BB*SS*DD) / (4*256)
#define NTW  4096    // 32*32*4
__global__ __launch_bounds__(256) void prep(
    const float* __restrict__ q, const float* __restrict__ k, const float* __restrict__ v,
    unsigned short* __restrict__ oq, unsigned short* __restrict__ ok,
    unsigned short* __restrict__ ov,
    const float* __restrict__ w0, const float* __restrict__ w1,
    const float* __restrict__ w2, const float* __restrict__ w3,
    unsigned short* __restrict__ t0, unsigned short* __restrict__ t1,
    unsigned short* __restrict__ t2, unsigned short* __restrict__ t3,
    const int* __restrict__ skip, int* __restrict__ posk, int* __restrict__ nval) {
  __shared__ __align__(16) unsigned short tile[64 * 76];
  __shared__ int cnts[64], offs[64];
  const int bid = blockIdx.x;
  const int tx = threadIdx.x;

  if (bid < NCVT) {
    const int nq = BB * MAXL * DD / 4, nk = BB * SS * DD / 4;
    int idx = bid * 256 + tx;
    const float* src; unsigned short* dst; int off;
    if (idx < nq) { src = q; dst = oq; off = idx; }
    else if (idx < nq + nk) { src = k; dst = ok; off = idx - nq; }
    else { src = v; dst = ov; off = idx - nq - nk; }
    float4 vv = ((const float4*)src)[off];
    ushort4 hh;
    hh.x = f2bf(vv.x); hh.y = f2bf(vv.y); hh.z = f2bf(vv.z); hh.w = f2bf(vv.w);
    ((ushort4*)dst)[off] = hh;
  } else if (bid < NCVT + NTW) {
    int rem = bid - NCVT;
    int z = rem >> 10, r2 = rem & 1023;
    int bx = r2 & 31, by = r2 >> 5;
    const float* W; unsigned short* Wt;
    switch (z) {
      case 0: W = w0; Wt = t0; break;
      case 1: W = w1; Wt = t1; break;
      case 2: W = w2; Wt = t2; break;
      default: W = w3; Wt = t3; break;
    }
    int K0 = by * 64, N0 = bx * 64;
    #pragma unroll
    for (int i = 0; i < 4; i++) {
      int r = (tx >> 4) + i * 16, c4 = (tx & 15) * 4;
      float4 vv = *(const float4*)&W[(size_t)(K0 + r) * DD + N0 + c4];
      ushort4 hh;
      hh.x = f2bf(vv.x); hh.y = f2bf(vv.y); hh.z = f2bf(vv.z); hh.w = f2bf(vv.w);
      *(ushort4*)&tile[r * 76 + c4] = hh;
    }
    __syncthreads();
    #pragma unroll
    for (int i = 0; i < 4; i++) {
      int n = (tx >> 4) + i * 16, k4 = (tx & 15) * 4;
      ushort4 hh;
      hh.x = tile[(k4 + 0) * 76 + n];
      hh.y = tile[(k4 + 1) * 76 + n];
      hh.z = tile[(k4 + 2) * 76 + n];
      hh.w = tile[(k4 + 3) * 76 + n];
      *(ushort4*)&Wt[(size_t)(N0 + n) * DD + K0 + k4] = hh;
    }
  } else {
    int b = bid - (NCVT + NTW);
    const int* row = skip + b * SS;
    if (tx < 64) {
      int c = 0;
      for (int i = 0; i < 32; i++) c += (row[tx * 32 + i] != 0);
      cnts[tx] = c;
    }
    __syncthreads();
    if (tx == 0) {
      int run = 0;
      for (int i = 0; i < 64; i++) { offs[i] = run; run += cnts[i]; }
      nval[b] = run > MAXL ? MAXL : run;
    }
    __syncthreads();
    if (tx < 64) {
      int o = offs[tx];
      for (int i = 0; i < 32; i++)
        if (row[tx * 32 + i]) { if (o < MAXL) posk[b * MAXL + o] = tx * 32 + i; o++; }
      int nb = nval[b];
      for (int l = nb + tx; l < MAXL; l += 64) posk[b * MAXL + l] = -1;
    }
  }
}

// ---------------------------------------------------------------------------
// Fused Q/K/V projection: 256x256 tiles, grid (8,80). Swizzled by<16 -> Q
// (mode0,Lbits10), by<48 -> K (mode0,Lbits11), else V (mode2). Round-2 body
// verbatim: row-XOR LDS, coalesced global_load_lds dbuf, counted vmcnt,
// raw s_barrier phases, s_setprio. One launch keeps the machine full across
// all three GEMMs (tail overlap) and drops 2 launch gaps.
__global__ __launch_bounds__(512, 2) void gemm_proj(
    const unsigned short* __restrict__ Aq, const unsigned short* __restrict__ Bq,
    unsigned short* __restrict__ Cq,
    const unsigned short* __restrict__ Ak, const unsigned short* __restrict__ Bk,
    unsigned short* __restrict__ Ck,
    const unsigned short* __restrict__ Av, const unsigned short* __restrict__ Bv,
    unsigned short* __restrict__ Cv) {
  constexpr int K = DD;
  __shared__ __align__(16) unsigned short lds[65536];   // [2][256][64] A + B
  unsigned short* const Abuf = lds;
  unsigned short* const Bbuf = lds + 32768;

  const int tid = threadIdx.x;
  const int lane = tid & 63, quad = lane >> 4, c = lane & 15;
  const int w = tid >> 6;
  const int wm = (w >> 2) * 128, wn = (w & 3) * 64;

  // XCD swizzle over the full 640-block grid (640 % 8 == 0, bijective)
  const int nwg = gridDim.x * gridDim.y;
  const int bid0 = blockIdx.y * gridDim.x + blockIdx.x;
  const int cpx = nwg >> 3;
  const int bid = (bid0 & 7) * cpx + (bid0 >> 3);
  const int bx = bid & 7;
  const int by = bid >> 3;

  const unsigned short *A, *Bt;
  unsigned short* Cout;
  int mode, Lbits, lby;
  if (by < 16)      { A = Aq; Bt = Bq; Cout = Cq; mode = 0; Lbits = 10; lby = by; }
  else if (by < 48) { A = Ak; Bt = Bk; Cout = Ck; mode = 0; Lbits = 11; lby = by - 16; }
  else              { A = Av; Bt = Bv; Cout = Cv; mode = 2; Lbits = 11; lby = by - 48; }
  const size_t tm = (size_t)lby * 256, tn = (size_t)bx * 256;

  f32x4 acc[8][4] = {};

  const int trow = tid >> 3;
  const int tch = ((tid & 7) ^ (trow & 7)) * 8;
  const unsigned short* gA = A + (tm + trow) * (size_t)K + tch;
  const unsigned short* gB = Bt + (tn + trow) * (size_t)K + tch;

  auto STAGE = [&](int sel, int kk) {
    unsigned short* ad = Abuf + sel * 16384;
    unsigned short* bd = Bbuf + sel * 16384;
    #pragma unroll
    for (int i = 0; i < 4; i++)
      gl_lds16(gA + kk + (size_t)(i * 64) * K, ad + i * 4096 + tid * 8);
    #pragma unroll
    for (int i = 0; i < 4; i++)
      gl_lds16(gB + kk + (size_t)(i * 64) * K, bd + i * 4096 + tid * 8);
  };

  const int nkt = K >> 6;
  STAGE(0, 0);

  for (int t = 0; t < nkt; ++t) {
    const int sel = t & 1;
    const unsigned short* as = Abuf + sel * 16384;
    const unsigned short* bs = Bbuf + sel * 16384;
    if (t + 1 < nkt) {
      STAGE(sel ^ 1, (t + 1) << 6);
      asm volatile("s_waitcnt vmcnt(8)" ::: "memory");
    } else {
      asm volatile("s_waitcnt vmcnt(0)" ::: "memory");
    }
    __builtin_amdgcn_s_barrier();

    bf16x8 a0[4][2], b01[2][2], b23[2][2];
    // ---- P1
    #pragma unroll
    for (int i = 0; i < 4; i++)
      #pragma unroll
      for (int ks = 0; ks < 2; ks++)
        a0[i][ks] = ldfrag(&as[(wm + i * 16 + c) * 64 + (((ks * 4 + quad) ^ (c & 7)) << 3)]);
    #pragma unroll
    for (int j = 0; j < 2; j++)
      #pragma unroll
      for (int ks = 0; ks < 2; ks++)
        b01[j][ks] = ldfrag(&bs[(wn + j * 16 + c) * 64 + (((ks * 4 + quad) ^ (c & 7)) << 3)]);
    __builtin_amdgcn_s_barrier();
    __builtin_amdgcn_s_setprio(1);
    #pragma unroll
    for (int i = 0; i < 4; i++)
      #pragma unroll
      for (int j = 0; j < 2; j++)
        #pragma unroll
        for (int ks = 0; ks < 2; ks++)
          acc[i][j] = __builtin_amdgcn_mfma_f32_16x16x32_bf16(a0[i][ks], b01[j][ks], acc[i][j], 0, 0, 0);
    __builtin_amdgcn_s_setprio(0);
    __builtin_amdgcn_s_barrier();
    // ---- P2
    #pragma unroll
    for (int j = 0; j < 2; j++)
      #pragma unroll
      for (int ks = 0; ks < 2; ks++)
        b23[j][ks] = ldfrag(&bs[(wn + 32 + j * 16 + c) * 64 + (((ks * 4 + quad) ^ (c & 7)) << 3)]);
    __builtin_amdgcn_s_barrier();
    __builtin_amdgcn_s_setprio(1);
    #pragma unroll
    for (int i = 0; i < 4; i++)
      #pragma unroll
      for (int j = 0; j < 2; j++)
        #pragma unroll
        for (int ks = 0; ks < 2; ks++)
          acc[i][2 + j] = __builtin_amdgcn_mfma_f32_16x16x32_bf16(a0[i][ks], b23[j][ks], acc[i][2 + j], 0, 0, 0);
    __builtin_amdgcn_s_setprio(0);
    __builtin_amdgcn_s_barrier();
    // ---- P3
    bf16x8 a1[4][2];
    #pragma unroll
    for (int i = 0; i < 4; i++)
      #pragma unroll
      for (int ks = 0; ks < 2; ks++)
        a1[i][ks] = ldfrag(&as[(wm + 64 + i * 16 + c) * 64 + (((ks * 4 + quad) ^ (c & 7)) << 3)]);
    __builtin_amdgcn_s_barrier();
    __builtin_amdgcn_s_setprio(1);
    #pragma unroll
    for (int i = 0; i < 4; i++)
      #pragma unroll
      for (int j = 0; j < 2; j++)
        #pragma unroll
        for (int ks = 0; ks < 2; ks++)
          acc[4 + i][j] = __builtin_amdgcn_mfma_f32_16x16x32_bf16(a1[i][ks], b01[j][ks], acc[4 + i][j], 0, 0, 0);
    __builtin_amdgcn_s_setprio(0);
    __builtin_amdgcn_s_barrier();
    // ---- P4
    __builtin_amdgcn_s_setprio(1);
    #pragma unroll
    for (int i = 0; i < 4; i++)
      #pragma unroll
      for (int j = 0; j < 2; j++)
        #pragma unroll
        for (int ks = 0; ks < 2; ks++)
          acc[4 + i][2 + j] = __builtin_amdgcn_mfma_f32_16x16x32_bf16(a1[i][ks], b23[j][ks], acc[4 + i][2 + j], 0, 0, 0);
    __builtin_amdgcn_s_setprio(0);
    __builtin_amdgcn_s_barrier();
  }

  // ---- epilogue: per-wave [64][68] bounce tile in dead staging LDS
  unsigned short* ep = lds + w * 4352;
  const size_t Lmask = ((size_t)1 << Lbits) - 1;
  if (mode == 0) {
    #pragma unroll
    for (int mh = 0; mh < 2; mh++) {
      #pragma unroll
      for (int i = 0; i < 4; i++)
        #pragma unroll
        for (int j = 0; j < 4; j++)
          #pragma unroll
          for (int r = 0; r < 4; r++)
            ep[(i * 16 + quad * 4 + r) * 68 + j * 16 + c] = f2bf(acc[mh * 4 + i][j][r]);
      #pragma unroll
      for (int it = 0; it < 8; it++) {
        int chunk = it * 64 + lane;
        int ml = chunk >> 3, nc = (chunk & 7) * 8;
        uint4 val = *(const uint4*)&ep[ml * 68 + nc];
        size_t m = tm + wm + mh * 64 + ml, n = tn + wn + nc;
        size_t b = m >> Lbits, l = m & Lmask, h = n >> 7, d = n & 127;
        *(uint4*)&Cout[(((b * HH + h) << Lbits) + l) * 128 + d] = val;
      }
    }
  } else {
    #pragma unroll
    for (int mh = 0; mh < 2; mh++) {
      #pragma unroll
      for (int i = 0; i < 4; i++)
        #pragma unroll
        for (int j = 0; j < 4; j++)
          #pragma unroll
          for (int r = 0; r < 4; r++)
            ep[(j * 16 + c) * 68 + i * 16 + quad * 4 + r] = f2bf(acc[mh * 4 + i][j][r]);
      #pragma unroll
      for (int it = 0; it < 8; it++) {
        int chunk = it * 64 + lane;
        int nl = chunk >> 3, mc = (chunk & 7) * 8;
        uint4 val = *(const uint4*)&ep[nl * 68 + mc];
        size_t n = tn + wn + nl, m = tm + wm + mh * 64 + mc;
        size_t b = m >> 11, s = m & 2047, h = n >> 7, d = n & 127;
        *(uint4*)&Cout[((b * HH + h) * 128 + d) * SS + s] = val;
      }
    }
  }
}

// ---------------------------------------------------------------------------
// O-projection: 128x256 tile, grid (8,32) = 256 blocks. Round-2 verbatim.
__global__ __launch_bounds__(512, 2) void gemm_o(const unsigned short* __restrict__ A,
                                                 const unsigned short* __restrict__ Bt,
                                                 float* __restrict__ Cf,
                                                 int M, int N, int K) {
  __shared__ __align__(16) unsigned short lds[(128 + 256) * 64 * 2];
  unsigned short* const Abuf = lds;            // [2][128][64]
  unsigned short* const Bbuf = lds + 16384;    // [2][256][64]

  const int tid = threadIdx.x;
  const int lane = tid & 63, quad = lane >> 4, c = lane & 15;
  const int w = tid >> 6;
  const int wm = (w >> 2) * 64, wn = (w & 3) * 64;

  const int nwg = gridDim.x * gridDim.y;
  const int bid0 = blockIdx.y * gridDim.x + blockIdx.x;
  const int cpx = nwg >> 3;
  const int bid = (bid0 & 7) * cpx + (bid0 >> 3);
  const int bx = bid % gridDim.x;
  const int by = bid / gridDim.x;
  const size_t tm = (size_t)by * 128, tn = (size_t)bx * 256;

  f32x4 acc[4][4] = {};

  const int trow = tid >> 3;
  const int tch = ((tid & 7) ^ (trow & 7)) * 8;
  const unsigned short* gA = A + (tm + trow) * (size_t)K + tch;
  const unsigned short* gB = Bt + (tn + trow) * (size_t)K + tch;

  auto STAGE = [&](int sel, int kk) {
    unsigned short* ad = Abuf + sel * 8192;
    unsigned short* bd = Bbuf + sel * 16384;
    #pragma unroll
    for (int i = 0; i < 2; i++)
      gl_lds16(gA + kk + (size_t)(i * 64) * K, ad + i * 4096 + tid * 8);
    #pragma unroll
    for (int i = 0; i < 4; i++)
      gl_lds16(gB + kk + (size_t)(i * 64) * K, bd + i * 4096 + tid * 8);
  };

  const int nkt = K >> 6;
  STAGE(0, 0);

  for (int t = 0; t < nkt; ++t) {
    const int sel = t & 1;
    const unsigned short* as = Abuf + sel * 8192;
    const unsigned short* bs = Bbuf + sel * 16384;
    if (t + 1 < nkt) {
      STAGE(sel ^ 1, (t + 1) << 6);
      asm volatile("s_waitcnt vmcnt(6)" ::: "memory");
    } else {
      asm volatile("s_waitcnt vmcnt(0)" ::: "memory");
    }
    __builtin_amdgcn_s_barrier();

    bf16x8 a0[4][2], b01[2][2], b23[2][2];
    #pragma unroll
    for (int i = 0; i < 4; i++)
      #pragma unroll
      for (int ks = 0; ks < 2; ks++)
        a0[i][ks] = ldfrag(&as[(wm + i * 16 + c) * 64 + (((ks * 4 + quad) ^ (c & 7)) << 3)]);
    #pragma unroll
    for (int j = 0; j < 2; j++)
      #pragma unroll
      for (int ks = 0; ks < 2; ks++)
        b01[j][ks] = ldfrag(&bs[(wn + j * 16 + c) * 64 + (((ks * 4 + quad) ^ (c & 7)) << 3)]);
    __builtin_amdgcn_s_barrier();
    __builtin_amdgcn_s_setprio(1);
    #pragma unroll
    for (int i = 0; i < 4; i++)
      #pragma unroll
      for (int j = 0; j < 2; j++)
        #pragma unroll
        for (int ks = 0; ks < 2; ks++)
          acc[i][j] = __builtin_amdgcn_mfma_f32_16x16x32_bf16(a0[i][ks], b01[j][ks], acc[i][j], 0, 0, 0);
    __builtin_amdgcn_s_setprio(0);
    __builtin_amdgcn_s_barrier();
    #pragma unroll
    for (int j = 0; j < 2; j++)
      #pragma unroll
      for (int ks = 0; ks < 2; ks++)
        b23[j][ks] = ldfrag(&bs[(wn + 32 + j * 16 + c) * 64 + (((ks * 4 + quad) ^ (c & 7)) << 3)]);
    __builtin_amdgcn_s_barrier();
    __builtin_amdgcn_s_setprio(1);
    #pragma unroll
    for (int i = 0; i < 4; i++)
      #pragma unroll
      for (int j = 0; j < 2; j++)
        #pragma unroll
        for (int ks = 0; ks < 2; ks++)
          acc[i][2 + j] = __builtin_amdgcn_mfma_f32_16x16x32_bf16(a0[i][ks], b23[j][ks], acc[i][2 + j], 0, 0, 0);
    __builtin_amdgcn_s_setprio(0);
    __builtin_amdgcn_s_barrier();
  }

  #pragma unroll
  for (int i = 0; i < 4; i++)
    #pragma unroll
    for (int j = 0; j < 4; j++)
      #pragma unroll
      for (int r = 0; r < 4; r++) {
        size_t m = tm + wm + i * 16 + quad * 4 + r;
        size_t n = tn + wn + j * 16 + c;
        Cf[m * N + n] = acc[i][j][r];
      }
}

// ---------------------------------------------------------------------------
// fused RoPE. Q pre-scaled by 1/sqrt(128)*log2(e) (softmax runs base-2).
__global__ __launch_bounds__(256) void rope2(unsigned short* __restrict__ xq,
                                             unsigned short* __restrict__ xk,
                                             const int* __restrict__ posk) {
  constexpr float QSCL = (float)(0.08838834764831843 * 1.4426950408889634);
  const int Nq = BB * HH * MAXL * 64;
  int gid = blockIdx.x * 256 + threadIdx.x;
  unsigned short* x; int Lbits, idx, use_posk;
  if (gid < Nq) { x = xq; Lbits = 10; use_posk = 1; idx = gid; }
  else { x = xk; Lbits = 11; use_posk = 0; idx = gid - Nq; }
  int d = idx & 63;
  int rest = idx >> 6;
  int l = rest & ((1 << Lbits) - 1);
  int bh = rest >> Lbits;
  int b = bh >> 4;
  int p = use_posk ? posk[(b << 10) + l] : l;
  float ang = (float)p * __expf(-(float)d * 0.14391156831212787f); // ln(1e4)/64
  float sn, cs;
  __sincosf(ang, &sn, &cs);
  float S = use_posk ? QSCL : 1.0f;
  size_t base = (size_t)rest * 128;
  float x1 = bf2f(x[base + d]), x2 = bf2f(x[base + d + 64]);
  x[base + d]      = f2bf((x1 * cs - x2 * sn) * S);
  x[base + d + 64] = f2bf((x2 * cs + x1 * sn) * S);
}

// ---------------------------------------------------------------------------
// Flash attention, round-2 schedule with SINGLE-buffered K and V:
// LDS 16K (K) + 16K (V^T) + 9K (P) + km = 42 KB -> 3 blocks/CU (12 waves,
// +50% TLP vs round-2's 2 blocks — the lever round 5's A/B identified).
// 4-barrier schedule, exact counted vmcnt (issue-order audited):
//   top:   outstanding = K[t](4 old) + V[t](4 new) -> vmcnt(4) = K landed
//   mid:   after STG_K(t+1): V[t](4 old) + K[t+1](4 new) -> vmcnt(4) = V landed
// K[t+1] staged after the QK-reads-retired barrier; V[t+1] after the
// PV-reads-retired barrier (WAR safe). Never a full drain mid-loop.
// Coalesced row-XOR staging, DPP reduces, base-2 softmax, causal early-out.
__global__ __launch_bounds__(256) void attn_kernel(const unsigned short* __restrict__ qp,
                                                   const unsigned short* __restrict__ kp,
                                                   const unsigned short* __restrict__ vtp,
                                                   const int* __restrict__ posk,
                                                   const int* __restrict__ nval,
                                                   unsigned short* __restrict__ ctx) {
  __shared__ __align__(16) unsigned short k_s[64 * 128];   // [s][d] swizzled
  __shared__ __align__(16) unsigned short vt_s[128 * 64];  // [d][s] swizzled
  __shared__ __align__(16) unsigned short p_s[4 * 16 * 72];
  __shared__ int km_s[64];

  const int tid = threadIdx.x;
  const int w = tid >> 6, lane = tid & 63, quad = lane >> 4, c = lane & 15;
  const int bh = blockIdx.x, b = bh >> 4, h = bh & 15;
  const int qbase = blockIdx.y * 64;
  const int nb = nval[b];

  if (tid < 64) {
    int l = qbase + tid;
    km_s[tid] = (l < nb) ? posk[(b << 10) + l] : -1;
  }
  __syncthreads();   // drains the posk loads; vmcnt = 0 after this

  int lv = nb - 1 - qbase; lv = lv > 63 ? 63 : lv;
  const int tile_kmax = (lv >= 0) ? km_s[lv] : -1;
  const int nkt = (tile_kmax >= 0) ? ((tile_kmax >> 6) + 1) : 0;
  const bool whas = (w * 16 <= lv);
  int wl = w * 16 + 15; if (wl > lv) wl = lv;
  const int wkmax = whas ? km_s[wl] : -1;
  const int kminw = whas ? km_s[w * 16] : -1;
  int km[4];
  #pragma unroll
  for (int r = 0; r < 4; r++) km[r] = km_s[w * 16 + quad * 4 + r];

  // Q fragments in registers; pin so vmcnt accounting below is exact
  const unsigned short* qg = qp + (((size_t)bh << 10) + qbase) * 128;
  bf16x8 aq[4];
  #pragma unroll
  for (int ks = 0; ks < 4; ks++)
    aq[ks] = ldfrag(&qg[(size_t)(w * 16 + c) * 128 + ks * 32 + quad * 8]);
  asm volatile("" : "+v"(aq[0]), "+v"(aq[1]), "+v"(aq[2]), "+v"(aq[3]) :: "memory");

  // staging source pointers (row-XOR swizzle, fully coalesced wave loads)
  const int srow = tid >> 4;                       // K: s-local row 0..15 (+16i)
  const int kswz = (tid & 15) ^ (srow & 7);
  const unsigned short* kgp = kp + ((size_t)bh << 11) * 128 + (size_t)srow * 128 + kswz * 8;
  const int dvrow = tid >> 3;                      // V: d-local row 0..31 (+32i)
  const int vswz = (tid & 7) ^ (dvrow & 7);
  const unsigned short* vgp = vtp + ((size_t)bh * 128 + dvrow) * SS + vswz * 8;

  auto STG_K = [&](int kb) {
    #pragma unroll
    for (int i = 0; i < 4; i++)
      gl_lds16(kgp + ((size_t)kb + i * 16) * 128, &k_s[(i * 256 + tid) * 8]);
  };
  auto STG_V = [&](int kb) {
    #pragma unroll
    for (int i = 0; i < 4; i++)
      gl_lds16(vgp + (size_t)kb + (size_t)i * 32 * SS, &vt_s[(i * 256 + tid) * 8]);
  };

  float m_i[4], l_i[4];
  #pragma unroll
  for (int r = 0; r < 4; r++) { m_i[r] = -1e30f; l_i[r] = 0.f; }
  f32x4 o[8];
  #pragma unroll
  for (int dj = 0; dj < 8; dj++) o[dj] = (f32x4){0.f, 0.f, 0.f, 0.f};

  if (nkt > 0) { STG_K(0); STG_V(0); }

  for (int kt = 0; kt < nkt; kt++) {
    const int kb = kt * 64;
    const bool more = (kt + 1 < nkt);
    const bool act = (kb <= wkmax);

    // K[kt] landed: 4 oldest outstanding are K[kt]; 4 newest are V[kt]
    asm volatile("s_waitcnt vmcnt(4)" ::: "memory");
    __builtin_amdgcn_s_barrier();       // K visible block-wide

    f32x4 sa[4];
    if (act) {
      #pragma unroll
      for (int j = 0; j < 4; j++) {
        sa[j] = (f32x4){0.f, 0.f, 0.f, 0.f};
        #pragma unroll
        for (int ks = 0; ks < 4; ks++) {
          bf16x8 bk = ldfrag(&k_s[((j * 16 + c) << 7) + (((ks * 4 + quad) ^ (c & 7)) << 3)]);
          sa[j] = __builtin_amdgcn_mfma_f32_16x16x32_bf16(aq[ks], bk, sa[j], 0, 0, 0);
        }
      }
    }
    __builtin_amdgcn_s_barrier();       // all k_s reads retired
    if (more) STG_K(kb + 64);           // overwrite K buffer (WAR safe)

    if (act) {
      // online softmax, base-2 (Q pre-scaled by 1/sqrt(DH)*log2e)
      float mt[4] = {-1e30f, -1e30f, -1e30f, -1e30f};
      if (kb + 63 <= kminw) {           // fully visible tile: no masking
        #pragma unroll
        for (int j = 0; j < 4; j++)
          #pragma unroll
          for (int r = 0; r < 4; r++) mt[r] = fmaxf(mt[r], sa[j][r]);
      } else {
        #pragma unroll
        for (int j = 0; j < 4; j++) {
          int key = kb + j * 16 + c;
          #pragma unroll
          for (int r = 0; r < 4; r++) {
            float v = (key <= km[r]) ? sa[j][r] : -1e30f;
            sa[j][r] = v;
            mt[r] = fmaxf(mt[r], v);
          }
        }
      }
      float al[4], rs[4];
      #pragma unroll
      for (int r = 0; r < 4; r++) {
        mt[r] = rmax16(mt[r]);
        float mn = fmaxf(m_i[r], mt[r]);
        al[r] = __builtin_exp2f(m_i[r] - mn);
        m_i[r] = mn;
        rs[r] = 0.f;
      }
      #pragma unroll
      for (int j = 0; j < 4; j++)
        #pragma unroll
        for (int r = 0; r < 4; r++) {
          float pv = __builtin_exp2f(sa[j][r] - m_i[r]);
          sa[j][r] = pv;
          rs[r] += pv;
        }
      #pragma unroll
      for (int r = 0; r < 4; r++) {
        rs[r] = radd16(rs[r]);
        l_i[r] = l_i[r] * al[r] + rs[r];
      }
      #pragma unroll
      for (int dj = 0; dj < 8; dj++)
        #pragma unroll
        for (int r = 0; r < 4; r++) o[dj][r] *= al[r];
    }

    // V[kt] landed: outstanding = V[kt](4 old) + K[kt+1](4 new, if more)
    if (more) { asm volatile("s_waitcnt vmcnt(4)" ::: "memory"); }
    else      { asm volatile("s_waitcnt vmcnt(0)" ::: "memory"); }
    __builtin_amdgcn_s_barrier();       // V visible block-wide

    if (act) {
      // P: C-layout -> LDS -> A-layout (per-wave region)
      #pragma unroll
      for (int j = 0; j < 4; j++)
        #pragma unroll
        for (int r = 0; r < 4; r++)
          p_s[w * 1152 + (quad * 4 + r) * 72 + j * 16 + c] = f2bf(sa[j][r]);
      #pragma unroll
      for (int ks2 = 0; ks2 < 2; ks2++) {
        bf16x8 ap = ldfrag(&p_s[w * 1152 + c * 72 + ks2 * 32 + quad * 8]);
        #pragma unroll
        for (int dj = 0; dj < 8; dj++) {
          bf16x8 bv = ldfrag(&vt_s[((dj * 16 + c) << 6) + (((ks2 * 4 + quad) ^ (c & 7)) << 3)]);
          o[dj] = __builtin_amdgcn_mfma_f32_16x16x32_bf16(ap, bv, o[dj], 0, 0, 0);
        }
      }
    }
    __builtin_amdgcn_s_barrier();       // all vt_s reads retired
    if (more) STG_V(kb + 64);           // overwrite V buffer (WAR safe)
  }

  #pragma unroll
  for (int r = 0; r < 4; r++) {
    int l = qbase + w * 16 + quad * 4 + r;
    bool ok = (l < nb);
    float inv = ok ? (1.0f / l_i[r]) : 0.0f;
    #pragma unroll
    for (int dj = 0; dj < 8; dj++)
      ctx[(((size_t)b << 10) + l) * (size_t)DD + h * 128 + dj * 16 + c] =
          f2bf(ok ? o[dj][r] * inv : 0.0f);
  }
}

// ---------------------------------------------------------------------------
extern "C" void kernel_launch(void* const* d_in, const int* in_sizes, int n_in,
                              void* d_out, int out_size, void* d_ws, size_t ws_size,
                              hipStream_t stream) {
  const float* q_src = (const float*)d_in[0];
  const float* k_src = (const float*)d_in[1];
  const float* v_src = (const float*)d_in[2];
  const float* Wq = (const float*)d_in[3];
  const float* Wk = (const float*)d_in[4];
  const float* Wv = (const float*)d_in[5];
  const float* Wo = (const float*)d_in[6];
  const int* skip = (const int*)d_in[9];

  char* p = (char*)d_ws;
  auto alloc = [&](size_t bytes) -> char* {
    char* r = p;
    p += (bytes + 255) & ~(size_t)255;
    return r;
  };
  unsigned short* a_q  = (unsigned short*)alloc((size_t)BB * MAXL * DD * 2);
  unsigned short* a_k  = (unsigned short*)alloc((size_t)BB * SS * DD * 2);
  unsigned short* a_v  = (unsigned short*)alloc((size_t)BB * SS * DD * 2);
  unsigned short* wt_q = (unsigned short*)alloc((size_t)DD * DD * 2);
  unsigned short* wt_k = (unsigned short*)alloc((size_t)DD * DD * 2);
  unsigned short* wt_v = (unsigned short*)alloc((size_t)DD * DD * 2);
  unsigned short* wt_o = (unsigned short*)alloc((size_t)DD * DD * 2);
  unsigned short* q_pro = (unsigned short*)alloc((size_t)BB * HH * MAXL * DHD * 2);
  unsigned short* k_pro = (unsigned short*)alloc((size_t)BB * HH * SS * DHD * 2);
  unsigned short* v_t   = (unsigned short*)alloc((size_t)BB * HH * SS * DHD * 2);
  int* posk = (int*)alloc((size_t)BB * MAXL * 4);
  int* nval = (int*)alloc(64);
  unsigned short* ctx = a_q;  // a_q dead after Q projection

  prep<<<NCVT + NTW + BB, 256, 0, stream>>>(q_src, k_src, v_src, a_q, a_k, a_v,
                                            Wq, Wk, Wv, Wo, wt_q, wt_k, wt_v, wt_o,
                                            skip, posk, nval);

  gemm_proj<<<dim3(8, 80), 512, 0, stream>>>(a_q, wt_q, q_pro,
                                             a_k, wt_k, k_pro,
                                             a_v, wt_v, v_t);

  rope2<<<(BB * HH * (MAXL + SS) * 64) / 256, 256, 0, stream>>>(q_pro, k_pro, posk);

  attn_kernel<<<dim3(BB * HH, MAXL / 64), 256, 0, stream>>>(q_pro, k_pro, v_t, posk, nval, ctx);

  gemm_o<<<dim3(8, 32), 512, 0, stream>>>(ctx, wt_o, (float*)d_out, BB * MAXL, DD, DD);
}